// Round 2
// baseline (873.649 us; speedup 1.0000x reference)
//
#include <hip/hip_runtime.h>
#include <hip/hip_bf16.h>

// QuantumAttention: B=4, S=1024, E=1024, H=16, HD=64.
// Inputs/outputs fp32 (per reference); internal MFMA compute in bf16.
// d_out = [ out (4,194,304 f32) | probs_mixed (67,108,864 f32) ].
//
// R2 changes vs 755us:
//  - mix_kernel + legacy PV gemm -> single fused mixpv_kernel: reads unmixed
//    probs once, mixes in-register (mask-sparsity scalar-branched), writes
//    mixed f32 to d_out, stashes bf16 in swizzled LDS, PV-MFMAs to ctx.
//    Saves the 256MB PV re-read and the latency-bound 64^2 PV structure.
//  - q/k/v projection GEMMs batched into one z=3 launch (3 blocks/CU overlap).
//  - eff_weight/eff_bias pairs merged. 17 -> 9 dispatches.

#define S_ 1024
#define E_ 1024
#define H_ 16
#define HD_ 64
#define B_ 4

typedef __bf16 bf16x8 __attribute__((ext_vector_type(8)));
typedef __bf16 bf16x4 __attribute__((ext_vector_type(4)));
typedef __bf16 bf16x2 __attribute__((ext_vector_type(2)));
typedef float f32x4 __attribute__((ext_vector_type(4)));
typedef float f32x2 __attribute__((ext_vector_type(2)));

__device__ inline void stc(__bf16* p, float v) { *p = (__bf16)v; }
__device__ inline void stc(float* p, float v) { *p = v; }

// ---------- async global->LDS, 16B per lane (wave-uniform base + lane*16)
__device__ inline void gld16(const __bf16* g, __bf16* l) {
    __builtin_amdgcn_global_load_lds(
        (const __attribute__((address_space(1))) unsigned int*)g,
        (__attribute__((address_space(3))) unsigned int*)l,
        16, 0, 0);
}

// ---------- fp32 -> bf16 cast, 8 elems/thread, up to 3 tensors per launch
__global__ __launch_bounds__(256) void cast3_kernel(
    const float* __restrict__ a, const float* __restrict__ b2, const float* __restrict__ c,
    __bf16* __restrict__ oa, __bf16* __restrict__ ob, __bf16* __restrict__ oc)
{
    int which = blockIdx.y;
    const float* in = which == 0 ? a : (which == 1 ? b2 : c);
    __bf16* out = which == 0 ? oa : (which == 1 ? ob : oc);
    long i = ((long)blockIdx.x * 256 + threadIdx.x) * 8;
    f32x4 u0 = *(const f32x4*)(in + i);
    f32x4 u1 = *(const f32x4*)(in + i + 4);
    bf16x8 r;
    r[0] = (__bf16)u0[0]; r[1] = (__bf16)u0[1]; r[2] = (__bf16)u0[2]; r[3] = (__bf16)u0[3];
    r[4] = (__bf16)u1[0]; r[5] = (__bf16)u1[1]; r[6] = (__bf16)u1[2]; r[7] = (__bf16)u1[3];
    *(bf16x8*)(out + i) = r;
}

// ---------- Weff[h*64+e, j] = cos(phase[h,e]) * sum_d Had[d,e] * W[h*64+d, j]
// blockIdx.y selects (Wq->wqe) vs (Wk->wke)
__global__ __launch_bounds__(256) void eff_weight2_kernel(
    const float* __restrict__ Wq, const float* __restrict__ Wk,
    const float* __restrict__ had, const float* __restrict__ phase,
    __bf16* __restrict__ wqe, __bf16* __restrict__ wke)
{
    const float* W = blockIdx.y ? Wk : Wq;
    __bf16* Weff = blockIdx.y ? wke : wqe;
    int g = blockIdx.x * 256 + threadIdx.x;   // over E*E
    int row = g >> 10;                         // h*64+e
    int j = g & 1023;
    int h = row >> 6, e = row & 63;
    float c = cosf(phase[row]);
    float acc = 0.f;
#pragma unroll 8
    for (int d = 0; d < 64; ++d)
        acc += had[d * 64 + e] * W[(((h << 6) + d) << 10) + j];
    Weff[g] = (__bf16)(acc * c);
}

__global__ __launch_bounds__(256) void eff_bias2_kernel(
    const float* __restrict__ bq, const float* __restrict__ bk,
    const float* __restrict__ had, const float* __restrict__ phase,
    float* __restrict__ bqe, float* __restrict__ bke)
{
    const float* bvec = blockIdx.y ? bk : bq;
    float* beff = blockIdx.y ? bke : bqe;
    int row = blockIdx.x * 256 + threadIdx.x;  // over E
    int e = row & 63, h = row >> 6;
    float acc = 0.f;
#pragma unroll 8
    for (int d = 0; d < 64; ++d)
        acc += had[d * 64 + e] * bvec[(h << 6) + d];
    beff[row] = acc * cosf(phase[row]);
}

// ---------- m97-style tiled GEMM body: C = (A @ B^T) + bias
// A:[M,K] bf16, B:[N,K] bf16, C:[M,N]. 128x128 tile, BK=32, 4 waves (2x2),
// 4x4 16x16x32 fragments/wave, global_load_lds(16B) staging, 2-barrier loop.
template <typename CT>
__device__ __forceinline__ void gemm_bt_body(
    const __bf16* __restrict__ A, const __bf16* __restrict__ B,
    CT* __restrict__ C, const float* __restrict__ bias, int K, int ldc)
{
    __shared__ __bf16 As[128 * 32];   // 8 KB, row-major [128][32]
    __shared__ __bf16 Bs[128 * 32];   // 8 KB
    int t = threadIdx.x;
    int w = t >> 6, l = t & 63;
    int lm = l & 15, kq = l >> 4;
    int wm = w >> 1, wn = w & 1;
    long row0 = (long)blockIdx.x * 128;
    long col0 = (long)blockIdx.y * 128;

    int srow = l >> 2, skol = (l & 3) * 8;
    int c0i = w * 2, c1i = w * 2 + 1;
    const __bf16* gA0 = A + (row0 + c0i * 16 + srow) * (long)K + skol;
    const __bf16* gA1 = A + (row0 + c1i * 16 + srow) * (long)K + skol;
    const __bf16* gB0 = B + (col0 + c0i * 16 + srow) * (long)K + skol;
    const __bf16* gB1 = B + (col0 + c1i * 16 + srow) * (long)K + skol;
    __bf16* lA0 = &As[c0i * 512];
    __bf16* lA1 = &As[c1i * 512];
    __bf16* lB0 = &Bs[c0i * 512];
    __bf16* lB1 = &Bs[c1i * 512];

    f32x4 acc[4][4] = {};
    for (int k0 = 0; k0 < K; k0 += 32) {
        gld16(gA0 + k0, lA0);
        gld16(gA1 + k0, lA1);
        gld16(gB0 + k0, lB0);
        gld16(gB1 + k0, lB1);
        __syncthreads();
        bf16x8 af[4], bfr[4];
#pragma unroll
        for (int i = 0; i < 4; ++i)
            af[i] = *(const bf16x8*)&As[(wm * 64 + i * 16 + lm) * 32 + kq * 8];
#pragma unroll
        for (int j = 0; j < 4; ++j)
            bfr[j] = *(const bf16x8*)&Bs[(wn * 64 + j * 16 + lm) * 32 + kq * 8];
#pragma unroll
        for (int i = 0; i < 4; ++i)
#pragma unroll
            for (int j = 0; j < 4; ++j)
                acc[i][j] = __builtin_amdgcn_mfma_f32_16x16x32_bf16(af[i], bfr[j], acc[i][j], 0, 0, 0);
        __syncthreads();
    }

    // epilogue: C/D layout col=lane&15, row=(lane>>4)*4+reg  [m89-verified]
    long rbase = row0 + wm * 64 + kq * 4;
    long cbase = col0 + wn * 64 + lm;
#pragma unroll
    for (int i = 0; i < 4; ++i)
#pragma unroll
        for (int j = 0; j < 4; ++j) {
            long col = cbase + j * 16;
            float bv = bias ? bias[col] : 0.f;
#pragma unroll
            for (int rr = 0; rr < 4; ++rr) {
                long row = rbase + i * 16 + rr;
                stc(&C[row * (long)ldc + col], acc[i][j][rr] + bv);
            }
        }
}

template <typename CT>
__global__ __launch_bounds__(256) void gemm_one(
    const __bf16* __restrict__ A, const __bf16* __restrict__ B,
    CT* __restrict__ C, const float* __restrict__ bias, int K, int ldc)
{
    gemm_bt_body<CT>(A, B, C, bias, K, ldc);
}

// batched q/k/v projections: blockIdx.z selects the triple (3 blocks/CU overlap)
__global__ __launch_bounds__(256) void gemm_qkv(
    const __bf16* __restrict__ A0, const __bf16* __restrict__ B0, __bf16* __restrict__ C0, const float* __restrict__ bi0,
    const __bf16* __restrict__ A1, const __bf16* __restrict__ B1, __bf16* __restrict__ C1, const float* __restrict__ bi1,
    const __bf16* __restrict__ A2, const __bf16* __restrict__ B2, __bf16* __restrict__ C2, const float* __restrict__ bi2)
{
    int z = blockIdx.z;
    const __bf16* A = z == 0 ? A0 : (z == 1 ? A1 : A2);
    const __bf16* B = z == 0 ? B0 : (z == 1 ? B1 : B2);
    __bf16* C = z == 0 ? C0 : (z == 1 ? C1 : C2);
    const float* bi = z == 0 ? bi0 : (z == 1 ? bi1 : bi2);
    gemm_bt_body<__bf16>(A, B, C, bi, 1024, 1024);
}

// ---------- V2 [B,S,E] bf16 -> Vt [B,H,64,S] bf16
__global__ __launch_bounds__(256) void transpose_v(
    const __bf16* __restrict__ v2, __bf16* __restrict__ vt)
{
    int blk = blockIdx.x;            // b*256 + h*16 + st
    int st = blk & 15;
    int h = (blk >> 4) & 15;
    int b = blk >> 8;
    __shared__ __bf16 tile[64][72];
    int t = threadIdx.x;
    int sl = t >> 2, dc = (t & 3) * 16;
    const __bf16* src = v2 + ((long)(b * 1024 + st * 64 + sl)) * 1024 + h * 64 + dc;
    bf16x8 u0 = *(const bf16x8*)src;
    bf16x8 u1 = *(const bf16x8*)(src + 8);
#pragma unroll
    for (int j = 0; j < 8; ++j) { tile[sl][dc + j] = u0[j]; tile[sl][dc + 8 + j] = u1[j]; }
    __syncthreads();
    int dl = t >> 2, scn = (t & 3) * 16;
    __bf16* dst = vt + ((long)((b * 16 + h) * 64 + dl)) * 1024 + st * 64 + scn;
    bf16x8 o0, o1;
#pragma unroll
    for (int j = 0; j < 8; ++j) { o0[j] = tile[scn + j][dl]; o1[j] = tile[scn + 8 + j][dl]; }
    *(bf16x8*)dst = o0;
    *(bf16x8*)(dst + 8) = o1;
}

// ---------- fused scores + softmax, register-resident scores.
// grid: (S/16, 1, B*H); block 256 (4 waves). Writes UNMIXED probs (mixed later
// in-place by mixpv_kernel).
__global__ __launch_bounds__(256) void attn_kernel(
    const __bf16* __restrict__ Q2, const __bf16* __restrict__ K2,
    float* __restrict__ probs)
{
    __shared__ float redm[16][4] __attribute__((aligned(16)));
    __shared__ float reds[16][4] __attribute__((aligned(16)));
    int z = blockIdx.z;              // b*16 + h
    int b = z >> 4, h = z & 15;
    int qt = blockIdx.x;
    int w = threadIdx.x >> 6, l = threadIdx.x & 63;
    int q = l >> 4, lm = l & 15;
    int ko = q * 8;

    const __bf16* Qb = Q2 + (long)b * S_ * E_ + (long)h * 64;
    const __bf16* Kb = K2 + (long)b * S_ * E_ + (long)h * 64;

    const __bf16* pa = Qb + (long)(qt * 16 + lm) * E_ + ko;
    bf16x8 a0 = *(const bf16x8*)pa;
    bf16x8 a1 = *(const bf16x8*)(pa + 32);

    f32x4 acc[16];
#pragma unroll
    for (int f = 0; f < 16; ++f) {
        int n0 = w * 256 + f * 16;
        const __bf16* pb = Kb + (long)(n0 + lm) * E_ + ko;
        bf16x8 b0 = *(const bf16x8*)pb;
        bf16x8 b1 = *(const bf16x8*)(pb + 32);
        f32x4 tt = {0.f, 0.f, 0.f, 0.f};
        tt = __builtin_amdgcn_mfma_f32_16x16x32_bf16(a0, b0, tt, 0, 0, 0);
        tt = __builtin_amdgcn_mfma_f32_16x16x32_bf16(a1, b1, tt, 0, 0, 0);
        acc[f] = tt;
    }

    float m[4];
#pragma unroll
    for (int rr = 0; rr < 4; ++rr) {
        float mm = acc[0][rr];
#pragma unroll
        for (int f = 1; f < 16; ++f) mm = fmaxf(mm, acc[f][rr]);
#pragma unroll
        for (int off = 1; off < 16; off <<= 1) mm = fmaxf(mm, __shfl_xor(mm, off, 64));
        m[rr] = mm;
    }
    if (lm == 0) {
#pragma unroll
        for (int rr = 0; rr < 4; ++rr) redm[q * 4 + rr][w] = m[rr];
    }
    __syncthreads();
#pragma unroll
    for (int rr = 0; rr < 4; ++rr) {
        f32x4 v = *(const f32x4*)redm[q * 4 + rr];
        m[rr] = fmaxf(fmaxf(v[0], v[1]), fmaxf(v[2], v[3]));
    }

    float s[4] = {0.f, 0.f, 0.f, 0.f};
#pragma unroll
    for (int f = 0; f < 16; ++f) {
        f32x4 tt = acc[f];
#pragma unroll
        for (int rr = 0; rr < 4; ++rr) {
            float p = __expf((tt[rr] - m[rr]) * 0.125f);
            tt[rr] = p;
            s[rr] += p;
        }
        acc[f] = tt;
    }
#pragma unroll
    for (int rr = 0; rr < 4; ++rr) {
#pragma unroll
        for (int off = 1; off < 16; off <<= 1) s[rr] += __shfl_xor(s[rr], off, 64);
    }
    if (lm == 0) {
#pragma unroll
        for (int rr = 0; rr < 4; ++rr) reds[q * 4 + rr][w] = s[rr];
    }
    __syncthreads();
    float inv[4];
#pragma unroll
    for (int rr = 0; rr < 4; ++rr) {
        f32x4 v = *(const f32x4*)reds[q * 4 + rr];
        inv[rr] = 1.0f / (v[0] + v[1] + v[2] + v[3]);
    }

    float* prow = probs + (long)z * S_ * S_ + (long)(qt * 16) * S_;
#pragma unroll
    for (int f = 0; f < 16; ++f) {
        int col = w * 256 + f * 16 + lm;
#pragma unroll
        for (int rr = 0; rr < 4; ++rr)
            prow[(long)(q * 4 + rr) * S_ + col] = acc[f][rr] * inv[rr];
    }
}

// ---------- fused mix + PV. grid (S/16, 1, B), block 512 (8 waves).
// Block owns (b, 16 q-rows). Per 64-k chunk:
//   mix:  thread (q=t>>5, kk=(t&31)*2) reads probs[all 16 h] f32x2 (in-place
//         safe: all reads before writes), mixes with mask (wave-uniform sparse
//         skip), writes mixed f32 to d_out, stashes bf16 in swizzled LDS.
//   PV:   wave w owns heads w*2,w*2+1; A = LDS mixed probs (16qx64k),
//         B = Vt[g] from global; acc[2][4] f32x4 over all 16 chunks.
// LDS swizzle (G4): physical byte-in-row = logical ^ ((row&7)<<4); both sides.
__global__ __launch_bounds__(512) void mixpv_kernel(
    float* __restrict__ probs, const __bf16* __restrict__ vt,
    const float* __restrict__ mask, __bf16* __restrict__ ctx)
{
    __shared__ __bf16 pm[16 * 16 * 64];   // [g][q][64k] swizzled, 32 KB
    int t = threadIdx.x;
    int w = t >> 6, l = t & 63;
    int lm = l & 15, kq = l >> 4;
    int b = blockIdx.z, qt = blockIdx.x;

    int mq = t >> 5, mkk = (t & 31) * 2;
    float* pbase = probs + ((long)b << 24) + (long)(qt * 16 + mq) * 1024 + mkk;
    const __bf16* vtb = vt + ((long)(b * 16 + w * 2)) * 65536;  // [2][64][1024]
    int swzw = (mq & 7) << 4;             // write-side row swizzle
    int swzr = (lm & 7) << 4;             // read-side row swizzle

    f32x4 acc[2][4] = {};

    for (int c = 0; c < 16; ++c) {
        int k0 = c * 64;
        // ---- mix (register-resident, mask-sparse)
        f32x2 mout[16];
#pragma unroll
        for (int g = 0; g < 16; ++g) mout[g] = (f32x2){0.f, 0.f};
#pragma unroll
        for (int hh = 0; hh < 16; ++hh) {
            f32x2 vv = *(const f32x2*)(pbase + ((long)hh << 20) + k0);
#pragma unroll
            for (int g = 0; g < 16; ++g) {
                float cw = mask[hh * 16 + g];   // uniform -> scalar branch
                if (cw != 0.f) mout[g] += vv * cw;
            }
        }
        __syncthreads();   // prev chunk's MFMA reads of pm are done
#pragma unroll
        for (int g = 0; g < 16; ++g) {
            *(f32x2*)(pbase + ((long)g << 20) + k0) = mout[g];
            bf16x2 pv; pv[0] = (__bf16)mout[g][0]; pv[1] = (__bf16)mout[g][1];
            int cb = (mkk * 2) ^ swzw;     // physical byte within 128B row
            *(bf16x2*)&pm[(g * 16 + mq) * 64 + (cb >> 1)] = pv;
        }
        __syncthreads();   // pm ready
        // ---- PV MFMA
#pragma unroll
        for (int gl = 0; gl < 2; ++gl) {
            int rowb = ((w * 2 + gl) * 16 + lm) * 64;
            bf16x8 a0 = *(const bf16x8*)&pm[rowb + (((kq * 16) ^ swzr) >> 1)];
            bf16x8 a1 = *(const bf16x8*)&pm[rowb + (((64 + kq * 16) ^ swzr) >> 1)];
            const __bf16* vg = vtb + gl * 65536 + k0 + kq * 8;
#pragma unroll
            for (int j = 0; j < 4; ++j) {
                bf16x8 b0 = *(const bf16x8*)(vg + (j * 16 + lm) * 1024);
                bf16x8 b1 = *(const bf16x8*)(vg + (j * 16 + lm) * 1024 + 32);
                acc[gl][j] = __builtin_amdgcn_mfma_f32_16x16x32_bf16(a0, b0, acc[gl][j], 0, 0, 0);
                acc[gl][j] = __builtin_amdgcn_mfma_f32_16x16x32_bf16(a1, b1, acc[gl][j], 0, 0, 0);
            }
        }
    }

    // epilogue: ctx[b, qt*16 + kq*4+rr, g*64 + j*16 + lm]
    long rb = (long)(b * 1024 + qt * 16 + kq * 4);
#pragma unroll
    for (int gl = 0; gl < 2; ++gl)
#pragma unroll
        for (int j = 0; j < 4; ++j) {
            long colb = (long)((w * 2 + gl) * 64 + j * 16 + lm);
#pragma unroll
            for (int rr = 0; rr < 4; ++rr)
                ctx[(rb + rr) * 1024 + colb] = (__bf16)acc[gl][j][rr];
        }
}

extern "C" void kernel_launch(void* const* d_in, const int* in_sizes, int n_in,
                              void* d_out, int out_size, void* d_ws, size_t ws_size,
                              hipStream_t stream) {
    (void)in_sizes; (void)n_in; (void)out_size; (void)ws_size;
    const float* query = (const float*)d_in[0];
    const float* key   = (const float*)d_in[1];
    const float* value = (const float*)d_in[2];
    const float* Wq    = (const float*)d_in[3];
    const float* bq    = (const float*)d_in[4];
    const float* Wk    = (const float*)d_in[5];
    const float* bk    = (const float*)d_in[6];
    const float* Wv    = (const float*)d_in[7];
    const float* bv    = (const float*)d_in[8];
    const float* Wo    = (const float*)d_in[9];
    const float* bo    = (const float*)d_in[10];
    const float* phase = (const float*)d_in[11];
    const float* had   = (const float*)d_in[12];
    const float* mask  = (const float*)d_in[13];

    // workspace layout (bf16 elems unless noted); ~56 MB total
    __bf16* wqe  = (__bf16*)d_ws;              // 1,048,576
    __bf16* wke  = wqe + 1048576;
    __bf16* wv16 = wke + 1048576;
    __bf16* wo16 = wv16 + 1048576;
    float*  bqe  = (float*)(wo16 + 1048576);   // 1024 f32
    float*  bke  = bqe + 1024;
    __bf16* q16  = (__bf16*)(bke + 1024);      // 4,194,304 each below
    __bf16* k16  = q16 + 4194304;
    __bf16* v16  = k16 + 4194304;
    __bf16* q2   = v16 + 4194304;
    __bf16* k2   = q2 + 4194304;
    __bf16* v2   = k2 + 4194304;
    __bf16* vt   = k16;   // alias: k16 dead after qkv GEMM
    __bf16* ctx  = q16;   // alias: q16 dead after qkv GEMM

    float* out   = (float*)d_out;
    float* probs = out + 4194304;

    cast3_kernel<<<dim3(2048, 3), 256, 0, stream>>>(query, key, value, q16, k16, v16);
    cast3_kernel<<<dim3(512, 2), 256, 0, stream>>>(Wv, Wo, nullptr, wv16, wo16, nullptr);

    eff_weight2_kernel<<<dim3(4096, 2), 256, 0, stream>>>(Wq, Wk, had, phase, wqe, wke);
    eff_bias2_kernel<<<dim3(4, 2), 256, 0, stream>>>(bq, bk, had, phase, bqe, bke);

    gemm_qkv<<<dim3(32, 8, 3), 256, 0, stream>>>(
        q16, wqe, q2, bqe,
        k16, wke, k2, bke,
        v16, wv16, v2, bv);

    transpose_v<<<1024, 256, 0, stream>>>(v2, vt);

    attn_kernel<<<dim3(64, 1, 64), 256, 0, stream>>>(q2, k2, probs);

    // fused mix (in-place on d_out probs) + PV -> ctx
    mixpv_kernel<<<dim3(64, 1, 4), 512, 0, stream>>>(probs, vt, mask, ctx);

    // out = ctx @ Wo^T + bo
    gemm_one<float><<<dim3(32, 8), 256, 0, stream>>>(ctx, wo16, out, bo, 1024, 1024);
}

// Round 3
// 653.877 us; speedup vs baseline: 1.3361x; 1.3361x over previous
//
#include <hip/hip_runtime.h>
#include <hip/hip_bf16.h>

// QuantumAttention: B=4, S=1024, E=1024, H=16, HD=64.
// Inputs/outputs fp32 (per reference); internal MFMA compute in bf16.
// d_out = [ out (4,194,304 f32) | probs_mixed (67,108,864 f32) ].
//
// R3 changes vs 874us (R2):
//  - mixpv rewritten as PAIR kernel: ent_mask is eye + one 0.2-partner per
//    head, so mixed[g] = c_gg*p[g] + c_prg*p[pr] (2 terms, not 16).
//    Block = (b, head-pair, 16 q-rows): coalesced f32x4 chunk reads of both
//    tiles, in-register mix, in-place f32 writes, 16KB swizzled LDS stash,
//    PV MFMA vs Vt. Grid 4096 (2048 active, 8/CU) vs R2's 256 -> TLP hides
//    latency; the 16-head 4MB-stride gather is gone.

#define S_ 1024
#define E_ 1024
#define H_ 16
#define HD_ 64
#define B_ 4

typedef __bf16 bf16x8 __attribute__((ext_vector_type(8)));
typedef __bf16 bf16x4 __attribute__((ext_vector_type(4)));
typedef __bf16 bf16x2 __attribute__((ext_vector_type(2)));
typedef float f32x4 __attribute__((ext_vector_type(4)));
typedef float f32x2 __attribute__((ext_vector_type(2)));

__device__ inline void stc(__bf16* p, float v) { *p = (__bf16)v; }
__device__ inline void stc(float* p, float v) { *p = v; }

// ---------- async global->LDS, 16B per lane (wave-uniform base + lane*16)
__device__ inline void gld16(const __bf16* g, __bf16* l) {
    __builtin_amdgcn_global_load_lds(
        (const __attribute__((address_space(1))) unsigned int*)g,
        (__attribute__((address_space(3))) unsigned int*)l,
        16, 0, 0);
}

// ---------- fp32 -> bf16 cast, 8 elems/thread, up to 3 tensors per launch
__global__ __launch_bounds__(256) void cast3_kernel(
    const float* __restrict__ a, const float* __restrict__ b2, const float* __restrict__ c,
    __bf16* __restrict__ oa, __bf16* __restrict__ ob, __bf16* __restrict__ oc)
{
    int which = blockIdx.y;
    const float* in = which == 0 ? a : (which == 1 ? b2 : c);
    __bf16* out = which == 0 ? oa : (which == 1 ? ob : oc);
    long i = ((long)blockIdx.x * 256 + threadIdx.x) * 8;
    f32x4 u0 = *(const f32x4*)(in + i);
    f32x4 u1 = *(const f32x4*)(in + i + 4);
    bf16x8 r;
    r[0] = (__bf16)u0[0]; r[1] = (__bf16)u0[1]; r[2] = (__bf16)u0[2]; r[3] = (__bf16)u0[3];
    r[4] = (__bf16)u1[0]; r[5] = (__bf16)u1[1]; r[6] = (__bf16)u1[2]; r[7] = (__bf16)u1[3];
    *(bf16x8*)(out + i) = r;
}

// ---------- Weff[h*64+e, j] = cos(phase[h,e]) * sum_d Had[d,e] * W[h*64+d, j]
// blockIdx.y selects (Wq->wqe) vs (Wk->wke)
__global__ __launch_bounds__(256) void eff_weight2_kernel(
    const float* __restrict__ Wq, const float* __restrict__ Wk,
    const float* __restrict__ had, const float* __restrict__ phase,
    __bf16* __restrict__ wqe, __bf16* __restrict__ wke)
{
    const float* W = blockIdx.y ? Wk : Wq;
    __bf16* Weff = blockIdx.y ? wke : wqe;
    int g = blockIdx.x * 256 + threadIdx.x;   // over E*E
    int row = g >> 10;                         // h*64+e
    int j = g & 1023;
    int h = row >> 6, e = row & 63;
    float c = cosf(phase[row]);
    float acc = 0.f;
#pragma unroll 8
    for (int d = 0; d < 64; ++d)
        acc += had[d * 64 + e] * W[(((h << 6) + d) << 10) + j];
    Weff[g] = (__bf16)(acc * c);
}

__global__ __launch_bounds__(256) void eff_bias2_kernel(
    const float* __restrict__ bq, const float* __restrict__ bk,
    const float* __restrict__ had, const float* __restrict__ phase,
    float* __restrict__ bqe, float* __restrict__ bke)
{
    const float* bvec = blockIdx.y ? bk : bq;
    float* beff = blockIdx.y ? bke : bqe;
    int row = blockIdx.x * 256 + threadIdx.x;  // over E
    int e = row & 63, h = row >> 6;
    float acc = 0.f;
#pragma unroll 8
    for (int d = 0; d < 64; ++d)
        acc += had[d * 64 + e] * bvec[(h << 6) + d];
    beff[row] = acc * cosf(phase[row]);
}

// ---------- m97-style tiled GEMM body: C = (A @ B^T) + bias
// A:[M,K] bf16, B:[N,K] bf16, C:[M,N]. 128x128 tile, BK=32, 4 waves (2x2),
// 4x4 16x16x32 fragments/wave, global_load_lds(16B) staging, 2-barrier loop.
template <typename CT>
__device__ __forceinline__ void gemm_bt_body(
    const __bf16* __restrict__ A, const __bf16* __restrict__ B,
    CT* __restrict__ C, const float* __restrict__ bias, int K, int ldc)
{
    __shared__ __bf16 As[128 * 32];   // 8 KB, row-major [128][32]
    __shared__ __bf16 Bs[128 * 32];   // 8 KB
    int t = threadIdx.x;
    int w = t >> 6, l = t & 63;
    int lm = l & 15, kq = l >> 4;
    int wm = w >> 1, wn = w & 1;
    long row0 = (long)blockIdx.x * 128;
    long col0 = (long)blockIdx.y * 128;

    int srow = l >> 2, skol = (l & 3) * 8;
    int c0i = w * 2, c1i = w * 2 + 1;
    const __bf16* gA0 = A + (row0 + c0i * 16 + srow) * (long)K + skol;
    const __bf16* gA1 = A + (row0 + c1i * 16 + srow) * (long)K + skol;
    const __bf16* gB0 = B + (col0 + c0i * 16 + srow) * (long)K + skol;
    const __bf16* gB1 = B + (col0 + c1i * 16 + srow) * (long)K + skol;
    __bf16* lA0 = &As[c0i * 512];
    __bf16* lA1 = &As[c1i * 512];
    __bf16* lB0 = &Bs[c0i * 512];
    __bf16* lB1 = &Bs[c1i * 512];

    f32x4 acc[4][4] = {};
    for (int k0 = 0; k0 < K; k0 += 32) {
        gld16(gA0 + k0, lA0);
        gld16(gA1 + k0, lA1);
        gld16(gB0 + k0, lB0);
        gld16(gB1 + k0, lB1);
        __syncthreads();
        bf16x8 af[4], bfr[4];
#pragma unroll
        for (int i = 0; i < 4; ++i)
            af[i] = *(const bf16x8*)&As[(wm * 64 + i * 16 + lm) * 32 + kq * 8];
#pragma unroll
        for (int j = 0; j < 4; ++j)
            bfr[j] = *(const bf16x8*)&Bs[(wn * 64 + j * 16 + lm) * 32 + kq * 8];
#pragma unroll
        for (int i = 0; i < 4; ++i)
#pragma unroll
            for (int j = 0; j < 4; ++j)
                acc[i][j] = __builtin_amdgcn_mfma_f32_16x16x32_bf16(af[i], bfr[j], acc[i][j], 0, 0, 0);
        __syncthreads();
    }

    // epilogue: C/D layout col=lane&15, row=(lane>>4)*4+reg  [m89-verified]
    long rbase = row0 + wm * 64 + kq * 4;
    long cbase = col0 + wn * 64 + lm;
#pragma unroll
    for (int i = 0; i < 4; ++i)
#pragma unroll
        for (int j = 0; j < 4; ++j) {
            long col = cbase + j * 16;
            float bv = bias ? bias[col] : 0.f;
#pragma unroll
            for (int rr = 0; rr < 4; ++rr) {
                long row = rbase + i * 16 + rr;
                stc(&C[row * (long)ldc + col], acc[i][j][rr] + bv);
            }
        }
}

template <typename CT>
__global__ __launch_bounds__(256) void gemm_one(
    const __bf16* __restrict__ A, const __bf16* __restrict__ B,
    CT* __restrict__ C, const float* __restrict__ bias, int K, int ldc)
{
    gemm_bt_body<CT>(A, B, C, bias, K, ldc);
}

// batched q/k/v projections: blockIdx.z selects the triple (3 blocks/CU overlap)
__global__ __launch_bounds__(256) void gemm_qkv(
    const __bf16* __restrict__ A0, const __bf16* __restrict__ B0, __bf16* __restrict__ C0, const float* __restrict__ bi0,
    const __bf16* __restrict__ A1, const __bf16* __restrict__ B1, __bf16* __restrict__ C1, const float* __restrict__ bi1,
    const __bf16* __restrict__ A2, const __bf16* __restrict__ B2, __bf16* __restrict__ C2, const float* __restrict__ bi2)
{
    int z = blockIdx.z;
    const __bf16* A = z == 0 ? A0 : (z == 1 ? A1 : A2);
    const __bf16* B = z == 0 ? B0 : (z == 1 ? B1 : B2);
    __bf16* C = z == 0 ? C0 : (z == 1 ? C1 : C2);
    const float* bi = z == 0 ? bi0 : (z == 1 ? bi1 : bi2);
    gemm_bt_body<__bf16>(A, B, C, bi, 1024, 1024);
}

// ---------- V2 [B,S,E] bf16 -> Vt [B,H,64,S] bf16
__global__ __launch_bounds__(256) void transpose_v(
    const __bf16* __restrict__ v2, __bf16* __restrict__ vt)
{
    int blk = blockIdx.x;            // b*256 + h*16 + st
    int st = blk & 15;
    int h = (blk >> 4) & 15;
    int b = blk >> 8;
    __shared__ __bf16 tile[64][72];
    int t = threadIdx.x;
    int sl = t >> 2, dc = (t & 3) * 16;
    const __bf16* src = v2 + ((long)(b * 1024 + st * 64 + sl)) * 1024 + h * 64 + dc;
    bf16x8 u0 = *(const bf16x8*)src;
    bf16x8 u1 = *(const bf16x8*)(src + 8);
#pragma unroll
    for (int j = 0; j < 8; ++j) { tile[sl][dc + j] = u0[j]; tile[sl][dc + 8 + j] = u1[j]; }
    __syncthreads();
    int dl = t >> 2, scn = (t & 3) * 16;
    __bf16* dst = vt + ((long)((b * 16 + h) * 64 + dl)) * 1024 + st * 64 + scn;
    bf16x8 o0, o1;
#pragma unroll
    for (int j = 0; j < 8; ++j) { o0[j] = tile[scn + j][dl]; o1[j] = tile[scn + 8 + j][dl]; }
    *(bf16x8*)dst = o0;
    *(bf16x8*)(dst + 8) = o1;
}

// ---------- fused scores + softmax, register-resident scores.
// grid: (S/16, 1, B*H); block 256 (4 waves). Writes UNMIXED probs f32
// into the d_out probs region (scratch; mixed in-place by mixpv2).
__global__ __launch_bounds__(256) void attn_kernel(
    const __bf16* __restrict__ Q2, const __bf16* __restrict__ K2,
    float* __restrict__ probs)
{
    __shared__ float redm[16][4] __attribute__((aligned(16)));
    __shared__ float reds[16][4] __attribute__((aligned(16)));
    int z = blockIdx.z;              // b*16 + h
    int b = z >> 4, h = z & 15;
    int qt = blockIdx.x;
    int w = threadIdx.x >> 6, l = threadIdx.x & 63;
    int q = l >> 4, lm = l & 15;
    int ko = q * 8;

    const __bf16* Qb = Q2 + (long)b * S_ * E_ + (long)h * 64;
    const __bf16* Kb = K2 + (long)b * S_ * E_ + (long)h * 64;

    const __bf16* pa = Qb + (long)(qt * 16 + lm) * E_ + ko;
    bf16x8 a0 = *(const bf16x8*)pa;
    bf16x8 a1 = *(const bf16x8*)(pa + 32);

    f32x4 acc[16];
#pragma unroll
    for (int f = 0; f < 16; ++f) {
        int n0 = w * 256 + f * 16;
        const __bf16* pb = Kb + (long)(n0 + lm) * E_ + ko;
        bf16x8 b0 = *(const bf16x8*)pb;
        bf16x8 b1 = *(const bf16x8*)(pb + 32);
        f32x4 tt = {0.f, 0.f, 0.f, 0.f};
        tt = __builtin_amdgcn_mfma_f32_16x16x32_bf16(a0, b0, tt, 0, 0, 0);
        tt = __builtin_amdgcn_mfma_f32_16x16x32_bf16(a1, b1, tt, 0, 0, 0);
        acc[f] = tt;
    }

    float m[4];
#pragma unroll
    for (int rr = 0; rr < 4; ++rr) {
        float mm = acc[0][rr];
#pragma unroll
        for (int f = 1; f < 16; ++f) mm = fmaxf(mm, acc[f][rr]);
#pragma unroll
        for (int off = 1; off < 16; off <<= 1) mm = fmaxf(mm, __shfl_xor(mm, off, 64));
        m[rr] = mm;
    }
    if (lm == 0) {
#pragma unroll
        for (int rr = 0; rr < 4; ++rr) redm[q * 4 + rr][w] = m[rr];
    }
    __syncthreads();
#pragma unroll
    for (int rr = 0; rr < 4; ++rr) {
        f32x4 v = *(const f32x4*)redm[q * 4 + rr];
        m[rr] = fmaxf(fmaxf(v[0], v[1]), fmaxf(v[2], v[3]));
    }

    float s[4] = {0.f, 0.f, 0.f, 0.f};
#pragma unroll
    for (int f = 0; f < 16; ++f) {
        f32x4 tt = acc[f];
#pragma unroll
        for (int rr = 0; rr < 4; ++rr) {
            float p = __expf((tt[rr] - m[rr]) * 0.125f);
            tt[rr] = p;
            s[rr] += p;
        }
        acc[f] = tt;
    }
#pragma unroll
    for (int rr = 0; rr < 4; ++rr) {
#pragma unroll
        for (int off = 1; off < 16; off <<= 1) s[rr] += __shfl_xor(s[rr], off, 64);
    }
    if (lm == 0) {
#pragma unroll
        for (int rr = 0; rr < 4; ++rr) reds[q * 4 + rr][w] = s[rr];
    }
    __syncthreads();
    float inv[4];
#pragma unroll
    for (int rr = 0; rr < 4; ++rr) {
        f32x4 v = *(const f32x4*)reds[q * 4 + rr];
        inv[rr] = 1.0f / (v[0] + v[1] + v[2] + v[3]);
    }

    float* prow = probs + (long)z * S_ * S_ + (long)(qt * 16) * S_;
#pragma unroll
    for (int f = 0; f < 16; ++f) {
        int col = w * 256 + f * 16 + lm;
#pragma unroll
        for (int rr = 0; rr < 4; ++rr)
            prow[(long)(q * 4 + rr) * S_ + col] = acc[f][rr] * inv[rr];
    }
}

// ---------- fused PAIR mix + PV. grid (S/16, 1, B*H), block 256 (4 waves).
// ent_mask = eye + one 0.2-partner per head => mixed[g] = c_gg*p[g]+c_prg*p[pr].
// Block (b, g, qt) with g < partner handles BOTH heads of the pair:
// per 256-k chunk: coalesced f32x4 reads of p[g],p[pr] tile rows, in-register
// 2-term mix, in-place f32 writes (block-self-contained), bf16 stash into
// 16KB XOR-swizzled LDS, PV MFMA vs Vt -> ctx. Blocks with g > partner exit.
__global__ __launch_bounds__(256) void mixpv2_kernel(
    float* __restrict__ probs, const __bf16* __restrict__ vt,
    const float* __restrict__ mask, __bf16* __restrict__ ctx)
{
    __shared__ float mm[256];
    __shared__ __bf16 pm[2][16][256];   // 16 KB, XOR-swizzled rows (512B)
    int t = threadIdx.x;
    mm[t] = mask[t];
    __syncthreads();
    int z = blockIdx.z;              // b*16 + g
    int b = z >> 4, g = z & 15;
    // partner: the row h != g with mask[h][g] != 0 (unique; eye+pairs)
    int pr = g;
#pragma unroll
    for (int j = 0; j < 16; ++j)
        if (j != g && mm[j * 16 + g] != 0.f) pr = j;
    if (pr < g) return;              // pair handled by the partner's block
    bool hasPr = (pr != g);
    float c_gg  = mm[g * 16 + g];
    float c_prg = hasPr ? mm[pr * 16 + g] : 0.f;   // weight of p[pr] in pm[g]
    float c_prpr = mm[pr * 16 + pr];
    float c_gpr = hasPr ? mm[g * 16 + pr] : 0.f;   // weight of p[g] in pm[pr]

    int qt = blockIdx.x;
    int w = t >> 6, l = t & 63;
    int lm = l & 15, kq = l >> 4;
    int r = t >> 4, cg = t & 15;     // mix role: row 0..15, col-group 0..15

    float* p1r = probs + ((long)(b * 16 + g) << 20) + (long)(qt * 16 + r) * 1024 + cg * 4;
    float* p2r = probs + ((long)(b * 16 + pr) << 20) + (long)(qt * 16 + r) * 1024 + cg * 4;
    int swzw = (r & 7) << 4;         // write-side LDS swizzle (bytes)
    int swzr = (lm & 7) << 4;        // read-side LDS swizzle (bytes)

    // PV role: wave w -> head (w>>1): 0=g,1=pr; d-half (w&1)
    int hsel = w >> 1, dh = w & 1;
    int hh = hsel ? pr : g;
    const __bf16* vbase = vt + ((long)(b * 16 + hh) * 64 + dh * 32) * 1024;
    f32x4 acc[2] = {};

    for (int c = 0; c < 4; ++c) {
        int k0 = c * 256;
        // ---- load both heads' chunk rows (coalesced 256B segments)
        f32x4 v1[4], v2[4];
#pragma unroll
        for (int j = 0; j < 4; ++j) v1[j] = *(const f32x4*)(p1r + k0 + j * 64);
        if (hasPr) {
#pragma unroll
            for (int j = 0; j < 4; ++j) v2[j] = *(const f32x4*)(p2r + k0 + j * 64);
        } else {
#pragma unroll
            for (int j = 0; j < 4; ++j) v2[j] = v1[j];
        }
        // ---- 2-term mix
        f32x4 o1[4], o2[4];
#pragma unroll
        for (int j = 0; j < 4; ++j) {
            o1[j] = v1[j] * c_gg + v2[j] * c_prg;
            o2[j] = v2[j] * c_prpr + v1[j] * c_gpr;
        }
        // ---- in-place mixed f32 writes (this block owns these rows)
#pragma unroll
        for (int j = 0; j < 4; ++j) *(f32x4*)(p1r + k0 + j * 64) = o1[j];
        if (hasPr) {
#pragma unroll
            for (int j = 0; j < 4; ++j) *(f32x4*)(p2r + k0 + j * 64) = o2[j];
        }
        __syncthreads();   // prev chunk's MFMA reads of pm done
        // ---- bf16 stash, swizzled: logical byte in row = col*2
#pragma unroll
        for (int j = 0; j < 4; ++j) {
            int lb = cg * 8 + j * 128;   // (cg*4 + j*64) cols * 2B
            bf16x4 s1, s2;
#pragma unroll
            for (int i = 0; i < 4; ++i) { s1[i] = (__bf16)o1[j][i]; s2[i] = (__bf16)o2[j][i]; }
            *(bf16x4*)((char*)&pm[0][r][0] + (lb ^ swzw)) = s1;
            *(bf16x4*)((char*)&pm[1][r][0] + (lb ^ swzw)) = s2;
        }
        __syncthreads();   // pm ready
        // ---- PV MFMA: ctx_pair[q, d] += pm[hsel] @ vt[hh]^T (chunk K=256)
#pragma unroll
        for (int ks = 0; ks < 8; ++ks) {
            int lb = (ks * 32 + kq * 8) * 2;
            bf16x8 af = *(const bf16x8*)((const char*)&pm[hsel][lm][0] + (lb ^ swzr));
            const __bf16* vp = vbase + k0 + ks * 32 + kq * 8;
#pragma unroll
            for (int j2 = 0; j2 < 2; ++j2) {
                bf16x8 bf = *(const bf16x8*)(vp + (long)(j2 * 16 + lm) * 1024);
                acc[j2] = __builtin_amdgcn_mfma_f32_16x16x32_bf16(af, bf, acc[j2], 0, 0, 0);
            }
        }
    }

    // epilogue: ctx[b, qt*16 + kq*4+rr, hh*64 + dh*32 + j2*16 + lm]
    long rb = (long)(b * 1024 + qt * 16 + kq * 4);
#pragma unroll
    for (int j2 = 0; j2 < 2; ++j2) {
        long col = (long)(hh * 64 + dh * 32 + j2 * 16 + lm);
#pragma unroll
        for (int rr = 0; rr < 4; ++rr)
            ctx[(rb + rr) * 1024 + col] = (__bf16)acc[j2][rr];
    }
}

extern "C" void kernel_launch(void* const* d_in, const int* in_sizes, int n_in,
                              void* d_out, int out_size, void* d_ws, size_t ws_size,
                              hipStream_t stream) {
    (void)in_sizes; (void)n_in; (void)out_size; (void)ws_size;
    const float* query = (const float*)d_in[0];
    const float* key   = (const float*)d_in[1];
    const float* value = (const float*)d_in[2];
    const float* Wq    = (const float*)d_in[3];
    const float* bq    = (const float*)d_in[4];
    const float* Wk    = (const float*)d_in[5];
    const float* bk    = (const float*)d_in[6];
    const float* Wv    = (const float*)d_in[7];
    const float* bv    = (const float*)d_in[8];
    const float* Wo    = (const float*)d_in[9];
    const float* bo    = (const float*)d_in[10];
    const float* phase = (const float*)d_in[11];
    const float* had   = (const float*)d_in[12];
    const float* mask  = (const float*)d_in[13];

    // workspace layout (bf16 elems unless noted); ~56 MB total
    __bf16* wqe  = (__bf16*)d_ws;              // 1,048,576
    __bf16* wke  = wqe + 1048576;
    __bf16* wv16 = wke + 1048576;
    __bf16* wo16 = wv16 + 1048576;
    float*  bqe  = (float*)(wo16 + 1048576);   // 1024 f32
    float*  bke  = bqe + 1024;
    __bf16* q16  = (__bf16*)(bke + 1024);      // 4,194,304 each below
    __bf16* k16  = q16 + 4194304;
    __bf16* v16  = k16 + 4194304;
    __bf16* q2   = v16 + 4194304;
    __bf16* k2   = q2 + 4194304;
    __bf16* v2   = k2 + 4194304;
    __bf16* vt   = k16;   // alias: k16 dead after qkv GEMM
    __bf16* ctx  = q16;   // alias: q16 dead after qkv GEMM

    float* out   = (float*)d_out;
    float* probs = out + 4194304;

    cast3_kernel<<<dim3(2048, 3), 256, 0, stream>>>(query, key, value, q16, k16, v16);
    cast3_kernel<<<dim3(512, 2), 256, 0, stream>>>(Wv, Wo, nullptr, wv16, wo16, nullptr);

    eff_weight2_kernel<<<dim3(4096, 2), 256, 0, stream>>>(Wq, Wk, had, phase, wqe, wke);
    eff_bias2_kernel<<<dim3(4, 2), 256, 0, stream>>>(bq, bk, had, phase, bqe, bke);

    gemm_qkv<<<dim3(32, 8, 3), 256, 0, stream>>>(
        q16, wqe, q2, bqe,
        k16, wke, k2, bke,
        v16, wv16, v2, bv);

    transpose_v<<<1024, 256, 0, stream>>>(v2, vt);

    attn_kernel<<<dim3(64, 1, 64), 256, 0, stream>>>(q2, k2, probs);

    // fused pair mix (in-place on d_out probs) + PV -> ctx
    mixpv2_kernel<<<dim3(64, 1, 64), 256, 0, stream>>>(probs, vt, mask, ctx);

    // out = ctx @ Wo^T + bo
    gemm_one<float><<<dim3(32, 8), 256, 0, stream>>>(ctx, wo16, out, bo, 1024, 1024);
}

// Round 5
// 608.899 us; speedup vs baseline: 1.4348x; 1.0739x over previous
//
#include <hip/hip_runtime.h>
#include <hip/hip_bf16.h>

// QuantumAttention: B=4, S=1024, E=1024, H=16, HD=64.
// Inputs/outputs fp32 (per reference); internal MFMA compute in bf16.
// d_out = [ out (4,194,304 f32) | probs_mixed (67,108,864 f32) ].
//
// R5 = R4 resubmit (container-level infra failure, no kernel verdict):
//  - attn_kernel + mixpv2 fused into attn_mixpv_kernel: block (b, head-pair,
//    16 q-rows), 512 thr. QK^T+softmax register-resident per head (4 waves
//    each); per 256-k chunk: LDS f32 dump -> 2-term mix -> ONLY mixed f32
//    written to HBM + swizzled bf16 pm -> PV MFMA vs Vt. Deletes the 256MB
//    unmixed write + 256MB re-read and one launch.

#define S_ 1024
#define E_ 1024
#define H_ 16
#define HD_ 64
#define B_ 4

typedef __bf16 bf16x8 __attribute__((ext_vector_type(8)));
typedef __bf16 bf16x4 __attribute__((ext_vector_type(4)));
typedef float f32x4 __attribute__((ext_vector_type(4)));

__device__ inline void stc(__bf16* p, float v) { *p = (__bf16)v; }
__device__ inline void stc(float* p, float v) { *p = v; }

// ---------- async global->LDS, 16B per lane (wave-uniform base + lane*16)
__device__ inline void gld16(const __bf16* g, __bf16* l) {
    __builtin_amdgcn_global_load_lds(
        (const __attribute__((address_space(1))) unsigned int*)g,
        (__attribute__((address_space(3))) unsigned int*)l,
        16, 0, 0);
}

// ---------- fp32 -> bf16 cast, 8 elems/thread, up to 3 tensors per launch
__global__ __launch_bounds__(256) void cast3_kernel(
    const float* __restrict__ a, const float* __restrict__ b2, const float* __restrict__ c,
    __bf16* __restrict__ oa, __bf16* __restrict__ ob, __bf16* __restrict__ oc)
{
    int which = blockIdx.y;
    const float* in = which == 0 ? a : (which == 1 ? b2 : c);
    __bf16* out = which == 0 ? oa : (which == 1 ? ob : oc);
    long i = ((long)blockIdx.x * 256 + threadIdx.x) * 8;
    f32x4 u0 = *(const f32x4*)(in + i);
    f32x4 u1 = *(const f32x4*)(in + i + 4);
    bf16x8 r;
    r[0] = (__bf16)u0[0]; r[1] = (__bf16)u0[1]; r[2] = (__bf16)u0[2]; r[3] = (__bf16)u0[3];
    r[4] = (__bf16)u1[0]; r[5] = (__bf16)u1[1]; r[6] = (__bf16)u1[2]; r[7] = (__bf16)u1[3];
    *(bf16x8*)(out + i) = r;
}

// ---------- Weff[h*64+e, j] = cos(phase[h,e]) * sum_d Had[d,e] * W[h*64+d, j]
__global__ __launch_bounds__(256) void eff_weight2_kernel(
    const float* __restrict__ Wq, const float* __restrict__ Wk,
    const float* __restrict__ had, const float* __restrict__ phase,
    __bf16* __restrict__ wqe, __bf16* __restrict__ wke)
{
    const float* W = blockIdx.y ? Wk : Wq;
    __bf16* Weff = blockIdx.y ? wke : wqe;
    int g = blockIdx.x * 256 + threadIdx.x;   // over E*E
    int row = g >> 10;                         // h*64+e
    int j = g & 1023;
    int h = row >> 6, e = row & 63;
    float c = cosf(phase[row]);
    float acc = 0.f;
#pragma unroll 8
    for (int d = 0; d < 64; ++d)
        acc += had[d * 64 + e] * W[(((h << 6) + d) << 10) + j];
    Weff[g] = (__bf16)(acc * c);
}

__global__ __launch_bounds__(256) void eff_bias2_kernel(
    const float* __restrict__ bq, const float* __restrict__ bk,
    const float* __restrict__ had, const float* __restrict__ phase,
    float* __restrict__ bqe, float* __restrict__ bke)
{
    const float* bvec = blockIdx.y ? bk : bq;
    float* beff = blockIdx.y ? bke : bqe;
    int row = blockIdx.x * 256 + threadIdx.x;  // over E
    int e = row & 63, h = row >> 6;
    float acc = 0.f;
#pragma unroll 8
    for (int d = 0; d < 64; ++d)
        acc += had[d * 64 + e] * bvec[(h << 6) + d];
    beff[row] = acc * cosf(phase[row]);
}

// ---------- m97-style tiled GEMM body: C = (A @ B^T) + bias
template <typename CT>
__device__ __forceinline__ void gemm_bt_body(
    const __bf16* __restrict__ A, const __bf16* __restrict__ B,
    CT* __restrict__ C, const float* __restrict__ bias, int K, int ldc)
{
    __shared__ __bf16 As[128 * 32];   // 8 KB, row-major [128][32]
    __shared__ __bf16 Bs[128 * 32];   // 8 KB
    int t = threadIdx.x;
    int w = t >> 6, l = t & 63;
    int lm = l & 15, kq = l >> 4;
    int wm = w >> 1, wn = w & 1;
    long row0 = (long)blockIdx.x * 128;
    long col0 = (long)blockIdx.y * 128;

    int srow = l >> 2, skol = (l & 3) * 8;
    int c0i = w * 2, c1i = w * 2 + 1;
    const __bf16* gA0 = A + (row0 + c0i * 16 + srow) * (long)K + skol;
    const __bf16* gA1 = A + (row0 + c1i * 16 + srow) * (long)K + skol;
    const __bf16* gB0 = B + (col0 + c0i * 16 + srow) * (long)K + skol;
    const __bf16* gB1 = B + (col0 + c1i * 16 + srow) * (long)K + skol;
    __bf16* lA0 = &As[c0i * 512];
    __bf16* lA1 = &As[c1i * 512];
    __bf16* lB0 = &Bs[c0i * 512];
    __bf16* lB1 = &Bs[c1i * 512];

    f32x4 acc[4][4] = {};
    for (int k0 = 0; k0 < K; k0 += 32) {
        gld16(gA0 + k0, lA0);
        gld16(gA1 + k0, lA1);
        gld16(gB0 + k0, lB0);
        gld16(gB1 + k0, lB1);
        __syncthreads();
        bf16x8 af[4], bfr[4];
#pragma unroll
        for (int i = 0; i < 4; ++i)
            af[i] = *(const bf16x8*)&As[(wm * 64 + i * 16 + lm) * 32 + kq * 8];
#pragma unroll
        for (int j = 0; j < 4; ++j)
            bfr[j] = *(const bf16x8*)&Bs[(wn * 64 + j * 16 + lm) * 32 + kq * 8];
#pragma unroll
        for (int i = 0; i < 4; ++i)
#pragma unroll
            for (int j = 0; j < 4; ++j)
                acc[i][j] = __builtin_amdgcn_mfma_f32_16x16x32_bf16(af[i], bfr[j], acc[i][j], 0, 0, 0);
        __syncthreads();
    }

    // epilogue: C/D layout col=lane&15, row=(lane>>4)*4+reg  [m89-verified]
    long rbase = row0 + wm * 64 + kq * 4;
    long cbase = col0 + wn * 64 + lm;
#pragma unroll
    for (int i = 0; i < 4; ++i)
#pragma unroll
        for (int j = 0; j < 4; ++j) {
            long col = cbase + j * 16;
            float bv = bias ? bias[col] : 0.f;
#pragma unroll
            for (int rr = 0; rr < 4; ++rr) {
                long row = rbase + i * 16 + rr;
                stc(&C[row * (long)ldc + col], acc[i][j][rr] + bv);
            }
        }
}

template <typename CT>
__global__ __launch_bounds__(256) void gemm_one(
    const __bf16* __restrict__ A, const __bf16* __restrict__ B,
    CT* __restrict__ C, const float* __restrict__ bias, int K, int ldc)
{
    gemm_bt_body<CT>(A, B, C, bias, K, ldc);
}

// batched q/k/v projections: blockIdx.z selects the triple (3 blocks/CU overlap)
__global__ __launch_bounds__(256) void gemm_qkv(
    const __bf16* __restrict__ A0, const __bf16* __restrict__ B0, __bf16* __restrict__ C0, const float* __restrict__ bi0,
    const __bf16* __restrict__ A1, const __bf16* __restrict__ B1, __bf16* __restrict__ C1, const float* __restrict__ bi1,
    const __bf16* __restrict__ A2, const __bf16* __restrict__ B2, __bf16* __restrict__ C2, const float* __restrict__ bi2)
{
    int z = blockIdx.z;
    const __bf16* A = z == 0 ? A0 : (z == 1 ? A1 : A2);
    const __bf16* B = z == 0 ? B0 : (z == 1 ? B1 : B2);
    __bf16* C = z == 0 ? C0 : (z == 1 ? C1 : C2);
    const float* bi = z == 0 ? bi0 : (z == 1 ? bi1 : bi2);
    gemm_bt_body<__bf16>(A, B, C, bi, 1024, 1024);
}

// ---------- V2 [B,S,E] bf16 -> Vt [B,H,64,S] bf16
__global__ __launch_bounds__(256) void transpose_v(
    const __bf16* __restrict__ v2, __bf16* __restrict__ vt)
{
    int blk = blockIdx.x;            // b*256 + h*16 + st
    int st = blk & 15;
    int h = (blk >> 4) & 15;
    int b = blk >> 8;
    __shared__ __bf16 tile[64][72];
    int t = threadIdx.x;
    int sl = t >> 2, dc = (t & 3) * 16;
    const __bf16* src = v2 + ((long)(b * 1024 + st * 64 + sl)) * 1024 + h * 64 + dc;
    bf16x8 u0 = *(const bf16x8*)src;
    bf16x8 u1 = *(const bf16x8*)(src + 8);
#pragma unroll
    for (int j = 0; j < 8; ++j) { tile[sl][dc + j] = u0[j]; tile[sl][dc + 8 + j] = u1[j]; }
    __syncthreads();
    int dl = t >> 2, scn = (t & 3) * 16;
    __bf16* dst = vt + ((long)((b * 16 + h) * 64 + dl)) * 1024 + st * 64 + scn;
    bf16x8 o0, o1;
#pragma unroll
    for (int j = 0; j < 8; ++j) { o0[j] = tile[scn + j][dl]; o1[j] = tile[scn + 8 + j][dl]; }
    *(bf16x8*)dst = o0;
    *(bf16x8*)(dst + 8) = o1;
}

// ---------- fused QK^T + softmax + pair-mix + PV.
// grid (S/16, 1, B*8), block 512 (8 waves). Block = (b, head-pair pi, 16 q).
// Waves 0-3: head g, keys [wi*256,+256); waves 4-7: head pr. Scores stay in
// registers (acc[16] f32x4/lane). Per 256-k chunk: owning wave dumps f32
// normalized probs to sc; 512 threads 2-term mix -> mixed f32 to d_out +
// swizzled bf16 pm; PV MFMA vs Vt. Only MIXED probs ever touch HBM.
__global__ __launch_bounds__(512, 4) void attn_mixpv_kernel(
    const __bf16* __restrict__ Q2, const __bf16* __restrict__ K2,
    const __bf16* __restrict__ vt, const float* __restrict__ mask,
    float* __restrict__ probs, __bf16* __restrict__ ctx)
{
    __shared__ float mmk[256];
    __shared__ float sc[2][16][264];          // f32 probs chunk, padded rows
    __shared__ __bf16 pm[2][16][256];         // mixed bf16, row-XOR-swizzled
    __shared__ float redm[2][16][4] __attribute__((aligned(16)));
    __shared__ float reds[2][16][4] __attribute__((aligned(16)));

    int t = threadIdx.x;
    if (t < 256) mmk[t] = mask[t];
    __syncthreads();

    int z = blockIdx.z;              // b*8 + pi
    int b = z >> 3, pi = z & 7;
    // enumerate head-groups (g, partner>=g); pick the pi-th
    int g = 0, pr = 0, cnt = 0;
    bool found = false;
    for (int gg = 0; gg < 16; ++gg) {
        int p2 = gg;
        for (int j = 0; j < 16; ++j)
            if (j != gg && mmk[j * 16 + gg] != 0.f) p2 = j;
        if (p2 >= gg) { if (cnt == pi) { g = gg; pr = p2; found = true; } ++cnt; }
    }
    if (!found) return;              // uniform across block
    bool hasPr = (pr != g);
    float c_gg   = mmk[g * 16 + g];
    float c_prg  = hasPr ? mmk[pr * 16 + g] : 0.f;   // weight of p[pr] in mixed[g]
    float c_prpr = mmk[pr * 16 + pr];
    float c_gpr  = hasPr ? mmk[g * 16 + pr] : 0.f;   // weight of p[g] in mixed[pr]

    int qt = blockIdx.x;
    int w = t >> 6, l = t & 63;
    int lm = l & 15, kq = l >> 4, ko = kq * 8;
    int hg = w >> 2, wi = w & 3;     // head-group (0=g,1=pr), wave-in-head
    int hh = hg ? pr : g;

    // ---- QK^T: wave covers keys [wi*256, wi*256+256), 16 f-tiles
    const __bf16* pa = Q2 + (long)b * S_ * E_ + (long)(qt * 16 + lm) * E_ + hh * 64 + ko;
    bf16x8 a0 = *(const bf16x8*)pa;
    bf16x8 a1 = *(const bf16x8*)(pa + 32);
    const __bf16* Kb = K2 + (long)b * S_ * E_ + (long)hh * 64;

    f32x4 acc[16];
#pragma unroll
    for (int f = 0; f < 16; ++f) {
        int n0 = wi * 256 + f * 16;
        const __bf16* pb = Kb + (long)(n0 + lm) * E_ + ko;
        bf16x8 b0 = *(const bf16x8*)pb;
        bf16x8 b1 = *(const bf16x8*)(pb + 32);
        f32x4 tt = {0.f, 0.f, 0.f, 0.f};
        tt = __builtin_amdgcn_mfma_f32_16x16x32_bf16(a0, b0, tt, 0, 0, 0);
        tt = __builtin_amdgcn_mfma_f32_16x16x32_bf16(a1, b1, tt, 0, 0, 0);
        acc[f] = tt;
    }

    // ---- softmax over 1024 keys, 4 waves per head; lane rows = kq*4+rr
    float m[4];
#pragma unroll
    for (int rr = 0; rr < 4; ++rr) {
        float mm = acc[0][rr];
#pragma unroll
        for (int f = 1; f < 16; ++f) mm = fmaxf(mm, acc[f][rr]);
#pragma unroll
        for (int off = 1; off < 16; off <<= 1) mm = fmaxf(mm, __shfl_xor(mm, off, 64));
        m[rr] = mm;
    }
    if (lm == 0) {
#pragma unroll
        for (int rr = 0; rr < 4; ++rr) redm[hg][kq * 4 + rr][wi] = m[rr];
    }
    __syncthreads();
#pragma unroll
    for (int rr = 0; rr < 4; ++rr) {
        f32x4 v = *(const f32x4*)redm[hg][kq * 4 + rr];
        m[rr] = fmaxf(fmaxf(v[0], v[1]), fmaxf(v[2], v[3]));
    }
    float s[4] = {0.f, 0.f, 0.f, 0.f};
#pragma unroll
    for (int f = 0; f < 16; ++f) {
#pragma unroll
        for (int rr = 0; rr < 4; ++rr) {
            float p = __expf((acc[f][rr] - m[rr]) * 0.125f);
            acc[f][rr] = p;
            s[rr] += p;
        }
    }
#pragma unroll
    for (int rr = 0; rr < 4; ++rr) {
#pragma unroll
        for (int off = 1; off < 16; off <<= 1) s[rr] += __shfl_xor(s[rr], off, 64);
    }
    if (lm == 0) {
#pragma unroll
        for (int rr = 0; rr < 4; ++rr) reds[hg][kq * 4 + rr][wi] = s[rr];
    }
    __syncthreads();
#pragma unroll
    for (int rr = 0; rr < 4; ++rr) {
        f32x4 v = *(const f32x4*)reds[hg][kq * 4 + rr];
        float inv = 1.0f / (v[0] + v[1] + v[2] + v[3]);
#pragma unroll
        for (int f = 0; f < 16; ++f) acc[f][rr] *= inv;
    }

    // ---- chunked mix + PV
    int oh = t >> 8, mr = (t >> 4) & 15, cg = t & 15;   // mix roles
    float wA = oh ? c_gpr : c_gg;    // weight of p[g]
    float wB = oh ? c_prpr : c_prg;  // weight of p[pr]
    bool doW = (oh == 0) || hasPr;
    float* gout = probs + ((long)(b * 16 + (oh ? pr : g)) << 20)
                + (long)(qt * 16 + mr) * 1024 + cg * 16;
    int swzw = (mr & 7) << 4;
    int swzr = (lm & 7) << 4;
    const __bf16* vrow = vt + ((long)((b * 16 + hh) * 64 + wi * 16 + lm)) * 1024;
    bool doPV = (hg == 0) || hasPr;
    f32x4 pacc = {0.f, 0.f, 0.f, 0.f};

    for (int c = 0; c < 4; ++c) {
        __syncthreads();             // prev PV done reading pm; sc free
        if (wi == c) {               // dump this chunk's normalized f32 probs
#pragma unroll
            for (int f = 0; f < 16; ++f)
#pragma unroll
                for (int rr = 0; rr < 4; ++rr)
                    sc[hg][kq * 4 + rr][f * 16 + lm] = acc[f][rr];
        }
        __syncthreads();
        // mix: sc -> mixed f32 global + swizzled bf16 pm
#pragma unroll
        for (int j = 0; j < 4; ++j) {
            f32x4 p1 = *(const f32x4*)&sc[0][mr][cg * 16 + j * 4];
            f32x4 p2 = *(const f32x4*)&sc[1][mr][cg * 16 + j * 4];
            f32x4 o = p1 * wA + p2 * wB;
            if (doW) *(f32x4*)(gout + (long)c * 256 + j * 4) = o;
            bf16x4 ob;
            ob[0] = (__bf16)o[0]; ob[1] = (__bf16)o[1];
            ob[2] = (__bf16)o[2]; ob[3] = (__bf16)o[3];
            *(bf16x4*)((char*)&pm[oh][mr][0] + ((cg * 32 + j * 8) ^ swzw)) = ob;
        }
        __syncthreads();
        // PV: wave (hg,wi) -> ctx cols hh*64 + wi*16 + lm
        if (doPV) {
#pragma unroll
            for (int ks = 0; ks < 8; ++ks) {
                bf16x8 af = *(const bf16x8*)((const char*)&pm[hg][lm][0]
                                             + ((ks * 64 + kq * 16) ^ swzr));
                bf16x8 bf = *(const bf16x8*)(vrow + c * 256 + ks * 32 + ko);
                pacc = __builtin_amdgcn_mfma_f32_16x16x32_bf16(af, bf, pacc, 0, 0, 0);
            }
        }
    }

    if (doPV) {
        long rb = (long)(b * 1024 + qt * 16 + kq * 4);
        long colb = (long)(hh * 64 + wi * 16 + lm);
#pragma unroll
        for (int rr = 0; rr < 4; ++rr)
            ctx[(rb + rr) * 1024 + colb] = (__bf16)pacc[rr];
    }
}

extern "C" void kernel_launch(void* const* d_in, const int* in_sizes, int n_in,
                              void* d_out, int out_size, void* d_ws, size_t ws_size,
                              hipStream_t stream) {
    (void)in_sizes; (void)n_in; (void)out_size; (void)ws_size;
    const float* query = (const float*)d_in[0];
    const float* key   = (const float*)d_in[1];
    const float* value = (const float*)d_in[2];
    const float* Wq    = (const float*)d_in[3];
    const float* bq    = (const float*)d_in[4];
    const float* Wk    = (const float*)d_in[5];
    const float* bk    = (const float*)d_in[6];
    const float* Wv    = (const float*)d_in[7];
    const float* bv    = (const float*)d_in[8];
    const float* Wo    = (const float*)d_in[9];
    const float* bo    = (const float*)d_in[10];
    const float* phase = (const float*)d_in[11];
    const float* had   = (const float*)d_in[12];
    const float* mask  = (const float*)d_in[13];

    // workspace layout (bf16 elems unless noted); ~56 MB total
    __bf16* wqe  = (__bf16*)d_ws;              // 1,048,576
    __bf16* wke  = wqe + 1048576;
    __bf16* wv16 = wke + 1048576;
    __bf16* wo16 = wv16 + 1048576;
    float*  bqe  = (float*)(wo16 + 1048576);   // 1024 f32
    float*  bke  = bqe + 1024;
    __bf16* q16  = (__bf16*)(bke + 1024);      // 4,194,304 each below
    __bf16* k16  = q16 + 4194304;
    __bf16* v16  = k16 + 4194304;
    __bf16* q2   = v16 + 4194304;
    __bf16* k2   = q2 + 4194304;
    __bf16* v2   = k2 + 4194304;
    __bf16* vt   = k16;   // alias: k16 dead after qkv GEMM
    __bf16* ctx  = q16;   // alias: q16 dead after qkv GEMM

    float* out   = (float*)d_out;
    float* probs = out + 4194304;

    cast3_kernel<<<dim3(2048, 3), 256, 0, stream>>>(query, key, value, q16, k16, v16);
    cast3_kernel<<<dim3(512, 2), 256, 0, stream>>>(Wv, Wo, nullptr, wv16, wo16, nullptr);

    eff_weight2_kernel<<<dim3(4096, 2), 256, 0, stream>>>(Wq, Wk, had, phase, wqe, wke);
    eff_bias2_kernel<<<dim3(4, 2), 256, 0, stream>>>(bq, bk, had, phase, bqe, bke);

    gemm_qkv<<<dim3(32, 8, 3), 256, 0, stream>>>(
        q16, wqe, q2, bqe,
        k16, wke, k2, bke,
        v16, wv16, v2, bv);

    transpose_v<<<1024, 256, 0, stream>>>(v2, vt);

    // fused scores + softmax + pair-mix (writes mixed probs) + PV -> ctx
    attn_mixpv_kernel<<<dim3(64, 1, 32), 512, 0, stream>>>(q2, k2, vt, mask, probs, ctx);

    // out = ctx @ Wo^T + bo
    gemm_one<float><<<dim3(32, 8), 256, 0, stream>>>(ctx, wo16, out, bo, 1024, 1024);
}